// Round 16
// baseline (623.429 us; speedup 1.0000x reference)
//
#include <hip/hip_runtime.h>

typedef __bf16 bf16;
typedef bf16 bf16x4 __attribute__((ext_vector_type(4)));
typedef bf16 bf16x8 __attribute__((ext_vector_type(8)));
typedef float f32x4 __attribute__((ext_vector_type(4)));

static constexpr int BATCH = 16;
static constexpr int SEQ   = 2048;  // N
static constexpr int DH    = 512;   // H (== M)
static constexpr int ROWS  = BATCH * SEQ;  // 32768

__device__ __forceinline__ f32x4 mfma16(bf16x8 a, bf16x8 b, f32x4 c) {
    return __builtin_amdgcn_mfma_f32_16x16x32_bf16(a, b, c, 0, 0, 0);
}

// async global->LDS, 16B per lane. dst must be wave-uniform base (HW adds lane*16).
__device__ __forceinline__ void gl_lds16(const void* g, void* l) {
    __builtin_amdgcn_global_load_lds((const __attribute__((address_space(1))) void*)g,
                                     (__attribute__((address_space(3))) void*)l, 16, 0, 0);
}

// ---------------- fp32 -> bf16 (vectorized) ----------------
__global__ void cvt_bf16_kernel(const float* __restrict__ in, bf16* __restrict__ out, int n4) {
    int i = blockIdx.x * blockDim.x + threadIdx.x;
    const int stride = gridDim.x * blockDim.x;
    for (; i < n4; i += stride) {
        f32x4 f = *reinterpret_cast<const f32x4*>(in + (size_t)i * 4);
        bf16x4 o;
        o[0] = (bf16)f[0]; o[1] = (bf16)f[1]; o[2] = (bf16)f[2]; o[3] = (bf16)f[3];
        *reinterpret_cast<bf16x4*>(out + (size_t)i * 4) = o;
    }
}

// -------- all 5 weights [K=512][N=512] fp32 -> [N][K] bf16, one launch --------
__global__ void cvt_wT5_kernel(const float* __restrict__ w0, const float* __restrict__ w1,
                               const float* __restrict__ w2, const float* __restrict__ w3,
                               const float* __restrict__ w4, bf16* __restrict__ out) {
    const int t = blockIdx.y;
    const float* in = (t == 0) ? w0 : (t == 1) ? w1 : (t == 2) ? w2 : (t == 3) ? w3 : w4;
    int idx = blockIdx.x * 256 + threadIdx.x;  // idx = n*512 + k
    int n = idx >> 9, k = idx & 511;
    out[t * 262144 + idx] = (bf16)in[k * 512 + n];
}

// ---------------- GEMM: Y = relu(X[R,512] @ W[512,512] + b), LDS staged ----
template <int OMODE>
__global__ __launch_bounds__(256, 2)
void gemm_relu_kernel(const bf16* __restrict__ X, const bf16* __restrict__ Wt,
                      const float* __restrict__ bias,
                      bf16* __restrict__ Y, bf16* __restrict__ Yt,
                      float* __restrict__ Yf)
{
    __shared__ bf16 Xl[2][128 * 64];
    __shared__ bf16 Wl[2][128 * 64];

    const int tid = threadIdx.x;
    const int lane = tid & 63, wid = tid >> 6;
    const int wr = wid >> 1, wc = wid & 1;
    const int r0 = blockIdx.x * 128;
    const int c0 = blockIdx.y * 128;
    const int lrow = lane & 15, lhi = lane >> 4;

    const int srow = tid >> 3;                // 0..31 within call
    const int skb  = (tid & 7) ^ (srow & 7);  // pre-swizzled source block
    const int sdst = wid * 512;               // this wave's 1KB chunk

    auto stage = [&](int buf, int kc) {
        const bf16* xs = X + (size_t)r0 * 512 + kc * 64;
        const bf16* ws = Wt + (size_t)c0 * 512 + kc * 64;
        #pragma unroll
        for (int c = 0; c < 4; ++c) {
            const int row = c * 32 + srow;
            gl_lds16(xs + (size_t)row * 512 + skb * 8, &Xl[buf][c * 2048 + sdst]);
        }
        #pragma unroll
        for (int c = 0; c < 4; ++c) {
            const int row = c * 32 + srow;
            gl_lds16(ws + (size_t)row * 512 + skb * 8, &Wl[buf][c * 2048 + sdst]);
        }
    };

    f32x4 acc[4][4] = {};

    stage(0, 0);
    __syncthreads();

    for (int t = 0; t < 8; ++t) {
        const int buf = t & 1;
        if (t + 1 < 8) stage(buf ^ 1, t + 1);
        #pragma unroll
        for (int kk = 0; kk < 2; ++kk) {
            bf16x8 af[4], bfr[4];
            const int kb = kk * 4 + lhi;
            #pragma unroll
            for (int tt = 0; tt < 4; ++tt) {
                const int ra = wr * 64 + tt * 16 + lrow;
                af[tt] = *reinterpret_cast<const bf16x8*>(&Xl[buf][ra * 64 + ((kb ^ (ra & 7)) * 8)]);
            }
            #pragma unroll
            for (int tt = 0; tt < 4; ++tt) {
                const int rb = wc * 64 + tt * 16 + lrow;
                bfr[tt] = *reinterpret_cast<const bf16x8*>(&Wl[buf][rb * 64 + ((kb ^ (rb & 7)) * 8)]);
            }
            #pragma unroll
            for (int i = 0; i < 4; ++i)
                #pragma unroll
                for (int j = 0; j < 4; ++j)
                    acc[i][j] = mfma16(af[i], bfr[j], acc[i][j]);
        }
        __syncthreads();
    }

    #pragma unroll
    for (int i = 0; i < 4; ++i) {
        #pragma unroll
        for (int j = 0; j < 4; ++j) {
            const int col = c0 + wc * 64 + j * 16 + lrow;
            const float bb = bias[col];
            #pragma unroll
            for (int rg = 0; rg < 4; ++rg) {
                const int r = r0 + wr * 64 + i * 16 + lhi * 4 + rg;
                float y = acc[i][j][rg] + bb;
                y = y > 0.f ? y : 0.f;
                if (OMODE == 2) {
                    Yf[(size_t)r * 512 + col] = y;
                } else {
                    Y[(size_t)r * 512 + col] = (bf16)y;
                    if (OMODE == 1) {
                        const int bi = r >> 11, nn = r & 2047;
                        Yt[((size_t)bi * 512 + col) * 2048 + nn] = (bf16)y;
                    }
                }
            }
        }
    }
}

// ---------------- fused attention ----------------
// scores = (Q K^T) * (-A); att = softmax(scores); O = att @ V + V  (bf16 out)
// max==0 softmax (R12/R13-validated): q,k>=0 and A in [0,1) => scores<=0 =>
// p = exp(x) directly, l accumulated per-lane, reduced once at epilogue.
// NEW in R16: q-fragment REUSE. Wave (wr=wid>>2: 32 q-rows as qf[2][16],
// wc=wid&3: 16-col strip): each K fragment read from LDS feeds TWO MFMAs
// (ratio 0.5 vs 1.0) -> QK^T LDS traffic halves (128 vs 256 b128/iter/CU).
// LDS port (one per CU, 4 SIMDs) was the measured cap (MfmaUtil pinned ~17%).
// qf[2][16]=128 VGPR needs the 2-waves/EU unified budget (256 regs):
// amdgpu_waves_per_eu(2,2) targets exactly that (launch_bounds' 2nd arg is
// min-BLOCKS — R10 lesson — and didn't lift the allocator's 128 cap in R12).
// Register diet: av single-buffered (iter top), vf JIT per-kc in PV.
// Peak ~178 VGPR + 64 AGPR = 242 <= 256.
// Skeleton = R13 (330us baseline): K double-buffered (2x64KB), staged at iter
// top into buf^1; lgkm-only barriers; in-order vmcnt (stage -> av/vf issued
// later; exp's av wait completes the stage before B1). 2 barriers/iter.
__global__ __attribute__((amdgpu_flat_work_group_size(512, 512), amdgpu_waves_per_eu(2, 2)))
void attn_kernel(const bf16* __restrict__ Q, const bf16* __restrict__ K,
                 const bf16* __restrict__ Vt, const bf16* __restrict__ V,
                 const float* __restrict__ A, bf16* __restrict__ O)
{
    __shared__ bf16 K_lds[2][64 * 512];   // 2 x 64KB, XOR-swizzled rows
    __shared__ bf16 P_lds[64 * 72];       // 9KB, stride 72 (144B rows)
    __shared__ float sump_lds[4][64];     // per-strip l partials (epilogue only)

    const int tid = threadIdx.x;
    const int lane = tid & 63, wid = tid >> 6;
    const int wr = wid >> 2, wc = wid & 3;
    const int lrow = lane & 15, lhi = lane >> 4;

    // XCD x handles batches {2x, 2x+1}
    const int id = blockIdx.x;
    const int xcd = id & 7, j = id >> 3;
    const int bb = 2 * xcd + (j >> 5);
    const int n0 = (j & 31) * 64;

    const bf16* Kbase  = K + (size_t)bb * SEQ * DH;
    const bf16* Vtbase = Vt + (size_t)bb * DH * SEQ;
    const float* Abase = A + ((size_t)bb * SEQ + n0 + wr * 32 + lhi * 4) * SEQ + wc * 16 + lrow;

    // stage K[0] -> buf 0 (64 rows, 8 per wave)
    #pragma unroll
    for (int c = 0; c < 8; ++c) {
        const int row = wid * 8 + c;
        gl_lds16(Kbase + (size_t)row * DH + ((lane ^ (row & 7)) * 8), &K_lds[0][row * 512]);
    }

    // Q resident: TWO 16-row tiles per wave (rows wr*32 + t*16 + lrow). 128 VGPR.
    bf16x8 qf[2][16];
    {
        const bf16* qp = Q + (size_t)(bb * SEQ + n0 + wr * 32 + lrow) * DH + lhi * 8;
        #pragma unroll
        for (int t2 = 0; t2 < 2; ++t2)
            #pragma unroll
            for (int kk = 0; kk < 16; ++kk)
                qf[t2][kk] = *reinterpret_cast<const bf16x8*>(
                    qp + (size_t)t2 * 16 * DH + kk * 32);
    }

    float l_part[2][4] = {};   // per-lane denominator partials
    f32x4 acc[4][4] = {};      // [q-row-tile 0..3 = all 64 rows][h-tile of wid*64 slice]

    __syncthreads();  // K[0] drained + published

    for (int it = 0; it < 32; ++it) {
        const int m0 = it * 64;
        const int buf = it & 1;

        // stage K[it+1] -> other buffer (completes before B1 via exp's av wait;
        // in-order vmcnt: stage issued first, av after)
        if (it + 1 < 32) {
            #pragma unroll
            for (int c = 0; c < 8; ++c) {
                const int row = wid * 8 + c;
                gl_lds16(Kbase + (size_t)(m0 + 64 + row) * DH + ((lane ^ (row & 7)) * 8),
                         &K_lds[buf ^ 1][row * 512]);
            }
        }
        // A for this iter (8 scalar loads; QK^T covers most of the latency)
        float av[8];
        {
            const float* ap = Abase + m0;
            #pragma unroll
            for (int t2 = 0; t2 < 2; ++t2)
                #pragma unroll
                for (int rg = 0; rg < 4; ++rg)
                    av[t2 * 4 + rg] = ap[(size_t)(t2 * 16 + rg) * SEQ];
        }

        // ---- QK^T: S[2 x 16 rows x 16-col strip]; each k-frag feeds 2 MFMAs ----
        f32x4 s[2] = {};
        {
            const int kr = wc * 16 + lrow;
            #pragma unroll
            for (int kk = 0; kk < 16; ++kk) {
                const int ks = kk * 4 + lhi;
                bf16x8 kf = *reinterpret_cast<const bf16x8*>(
                    &K_lds[buf][kr * 512 + ((ks ^ (kr & 7)) * 8)]);
                s[0] = mfma16(qf[0][kk], kf, s[0]);
                s[1] = mfma16(qf[1][kk], kf, s[1]);
            }
        }

        // ---- p = exp(score * -A) (max==0); P -> LDS; l accumulate ----
        #pragma unroll
        for (int t2 = 0; t2 < 2; ++t2) {
            #pragma unroll
            for (int rg = 0; rg < 4; ++rg) {
                const float p = __expf(s[t2][rg] * (-av[t2 * 4 + rg]));
                const int row = wr * 32 + t2 * 16 + lhi * 4 + rg;
                P_lds[row * 72 + wc * 16 + lrow] = (bf16)p;
                l_part[t2][rg] += p;
            }
        }

        // B1: lgkm-only — P writes + K reads retired; VMEM stays in flight
        asm volatile("s_waitcnt lgkmcnt(0)" ::: "memory");
        __builtin_amdgcn_s_barrier();
        __builtin_amdgcn_sched_barrier(0);

        // ---- PV: P (LDS, ratio 0.25) x Vt (JIT regs per kc) ----
        {
            const bf16* vp = Vtbase + (size_t)(wid * 64 + lrow) * SEQ + m0 + lhi * 8;
            #pragma unroll
            for (int kc = 0; kc < 2; ++kc) {
                bf16x8 vf[4];
                #pragma unroll
                for (int ht = 0; ht < 4; ++ht)
                    vf[ht] = *reinterpret_cast<const bf16x8*>(
                        vp + (size_t)(ht * 16) * SEQ + kc * 32);
                #pragma unroll
                for (int t = 0; t < 4; ++t) {
                    const bf16x8 pf = *reinterpret_cast<const bf16x8*>(
                        &P_lds[(t * 16 + lrow) * 72 + kc * 32 + lhi * 8]);
                    #pragma unroll
                    for (int ht = 0; ht < 4; ++ht)
                        acc[t][ht] = mfma16(pf, vf[ht], acc[t][ht]);
                }
            }
        }

        // B2: lgkm-only — P reads retired (WAR for next writes); K[it+1] stage
        // already complete (pre-B1) -> published block-wide.
        asm volatile("s_waitcnt lgkmcnt(0)" ::: "memory");
        __builtin_amdgcn_s_barrier();
        __builtin_amdgcn_sched_barrier(0);
    }

    // ---- epilogue: reduce l over the 16 lrow lanes per strip, combine strips ----
    #pragma unroll
    for (int t2 = 0; t2 < 2; ++t2) {
        #pragma unroll
        for (int rg = 0; rg < 4; ++rg) {
            float sv = l_part[t2][rg];
            sv += __shfl_xor(sv, 1);
            sv += __shfl_xor(sv, 2);
            sv += __shfl_xor(sv, 4);
            sv += __shfl_xor(sv, 8);
            if (lrow == 0) sump_lds[wc][wr * 32 + t2 * 16 + lhi * 4 + rg] = sv;
        }
    }
    __syncthreads();

    // ---- /l, +V, store ----
    #pragma unroll
    for (int t = 0; t < 4; ++t) {
        #pragma unroll
        for (int rg = 0; rg < 4; ++rg) {
            const int row = t * 16 + lhi * 4 + rg;
            const float l = sump_lds[0][row] + sump_lds[1][row]
                          + sump_lds[2][row] + sump_lds[3][row];
            const float inv = 1.f / l;
            const size_t rbase = (size_t)(bb * SEQ + n0 + row) * DH;
            #pragma unroll
            for (int ht = 0; ht < 4; ++ht) {
                const int col = wid * 64 + ht * 16 + lrow;
                const float vv = (float)V[rbase + col];
                O[rbase + col] = (bf16)(acc[t][ht][rg] * inv + vv);
            }
        }
    }
}

extern "C" void kernel_launch(void* const* d_in, const int* in_sizes, int n_in,
                              void* d_out, int out_size, void* d_ws, size_t ws_size,
                              hipStream_t stream) {
    const float* A    = (const float*)d_in[0];
    const float* h    = (const float*)d_in[1];
    const float* Wv1  = (const float*)d_in[2];
    const float* bv1  = (const float*)d_in[3];
    const float* Wv2  = (const float*)d_in[4];
    const float* bv2  = (const float*)d_in[5];
    const float* Wk   = (const float*)d_in[6];   // NOTE: Wk before Wq in dict order
    const float* bk   = (const float*)d_in[7];
    const float* Wq   = (const float*)d_in[8];
    const float* bq   = (const float*)d_in[9];
    const float* Wout = (const float*)d_in[10];
    const float* bout = (const float*)d_in[11];
    float* out = (float*)d_out;

    char* ws = (char*)d_ws;
    const size_t SZ = (size_t)ROWS * 512 * sizeof(bf16);  // 33.5 MB
    bf16* hb   = (bf16*)(ws + 0 * SZ);  // h in bf16; later reused as attention output
    bf16* tq   = (bf16*)(ws + 1 * SZ);  // t = relu(h@Wv1), later overwritten with q
    bf16* kb   = (bf16*)(ws + 2 * SZ);
    bf16* vb   = (bf16*)(ws + 3 * SZ);
    bf16* vtb  = (bf16*)(ws + 4 * SZ);  // v transposed: [B][H][N]
    bf16* wbase = (bf16*)(ws + 5 * SZ); // 5 x 512KB bf16 weights
    bf16* Wv1t  = wbase + 0 * 262144;
    bf16* Wv2t  = wbase + 1 * 262144;
    bf16* Wqt   = wbase + 2 * 262144;
    bf16* Wkt   = wbase + 3 * 262144;
    bf16* Woutt = wbase + 4 * 262144;
    bf16* ob = hb;  // attention output aliases hb (hb dead after k projection)

    cvt_bf16_kernel<<<4096, 256, 0, stream>>>(h, hb, ROWS * 512 / 4);
    cvt_wT5_kernel<<<dim3(1024, 5), 256, 0, stream>>>(Wv1, Wv2, Wq, Wk, Wout, wbase);

    dim3 gg(ROWS / 128, 512 / 128);  // (256, 4)
    gemm_relu_kernel<0><<<gg, 256, 0, stream>>>(hb, Wv1t, bv1, tq, nullptr, nullptr);  // t
    gemm_relu_kernel<1><<<gg, 256, 0, stream>>>(tq, Wv2t, bv2, vb, vtb, nullptr);      // v + vT
    gemm_relu_kernel<0><<<gg, 256, 0, stream>>>(hb, Wqt, bq, tq, nullptr, nullptr);    // q (over t)
    gemm_relu_kernel<0><<<gg, 256, 0, stream>>>(hb, Wkt, bk, kb, nullptr, nullptr);    // k

    attn_kernel<<<dim3(512), 512, 0, stream>>>(tq, kb, vtb, vb, A, ob);

    gemm_relu_kernel<2><<<gg, 256, 0, stream>>>(ob, Woutt, bout, nullptr, nullptr, out);
}

// Round 17
// 507.847 us; speedup vs baseline: 1.2276x; 1.2276x over previous
//
#include <hip/hip_runtime.h>

typedef __bf16 bf16;
typedef bf16 bf16x4 __attribute__((ext_vector_type(4)));
typedef bf16 bf16x8 __attribute__((ext_vector_type(8)));
typedef float f32x4 __attribute__((ext_vector_type(4)));

static constexpr int BATCH = 16;
static constexpr int SEQ   = 2048;  // N
static constexpr int DH    = 512;   // H (== M)
static constexpr int ROWS  = BATCH * SEQ;  // 32768

__device__ __forceinline__ f32x4 mfma16(bf16x8 a, bf16x8 b, f32x4 c) {
    return __builtin_amdgcn_mfma_f32_16x16x32_bf16(a, b, c, 0, 0, 0);
}

// async global->LDS, 16B per lane. dst must be wave-uniform base (HW adds lane*16).
__device__ __forceinline__ void gl_lds16(const void* g, void* l) {
    __builtin_amdgcn_global_load_lds((const __attribute__((address_space(1))) void*)g,
                                     (__attribute__((address_space(3))) void*)l, 16, 0, 0);
}

// ---------------- fp32 -> bf16 (vectorized) ----------------
__global__ void cvt_bf16_kernel(const float* __restrict__ in, bf16* __restrict__ out, int n4) {
    int i = blockIdx.x * blockDim.x + threadIdx.x;
    const int stride = gridDim.x * blockDim.x;
    for (; i < n4; i += stride) {
        f32x4 f = *reinterpret_cast<const f32x4*>(in + (size_t)i * 4);
        bf16x4 o;
        o[0] = (bf16)f[0]; o[1] = (bf16)f[1]; o[2] = (bf16)f[2]; o[3] = (bf16)f[3];
        *reinterpret_cast<bf16x4*>(out + (size_t)i * 4) = o;
    }
}

// -------- all 5 weights [K=512][N=512] fp32 -> [N][K] bf16, one launch --------
__global__ void cvt_wT5_kernel(const float* __restrict__ w0, const float* __restrict__ w1,
                               const float* __restrict__ w2, const float* __restrict__ w3,
                               const float* __restrict__ w4, bf16* __restrict__ out) {
    const int t = blockIdx.y;
    const float* in = (t == 0) ? w0 : (t == 1) ? w1 : (t == 2) ? w2 : (t == 3) ? w3 : w4;
    int idx = blockIdx.x * 256 + threadIdx.x;  // idx = n*512 + k
    int n = idx >> 9, k = idx & 511;
    out[t * 262144 + idx] = (bf16)in[k * 512 + n];
}

// ---------------- GEMM: Y = relu(X[R,512] @ W[512,512] + b), LDS staged ----
// NEW (R17): counted-vmcnt pipeline — the per-K-step __syncthreads (which
// drained the just-issued next-tile stage to vmcnt(0)) is replaced by:
//   stage(nbuf) -> s_waitcnt vmcnt(8) (only PREVIOUS stage's 8 ops; the new 8
//   stay in flight) + s_barrier -> ds_read+MFMA -> lgkmcnt(0) + s_barrier.
// No vmcnt(0) inside the loop (T3/T4 pattern).
template <int OMODE>
__global__ __launch_bounds__(256, 2)
void gemm_relu_kernel(const bf16* __restrict__ X, const bf16* __restrict__ Wt,
                      const float* __restrict__ bias,
                      bf16* __restrict__ Y, bf16* __restrict__ Yt,
                      float* __restrict__ Yf)
{
    __shared__ bf16 Xl[2][128 * 64];
    __shared__ bf16 Wl[2][128 * 64];

    const int tid = threadIdx.x;
    const int lane = tid & 63, wid = tid >> 6;
    const int wr = wid >> 1, wc = wid & 1;
    const int r0 = blockIdx.x * 128;
    const int c0 = blockIdx.y * 128;
    const int lrow = lane & 15, lhi = lane >> 4;

    const int srow = tid >> 3;                // 0..31 within call
    const int skb  = (tid & 7) ^ (srow & 7);  // pre-swizzled source block
    const int sdst = wid * 512;               // this wave's 1KB chunk

    auto stage = [&](int buf, int kc) {       // 8 gl_lds16 per thread
        const bf16* xs = X + (size_t)r0 * 512 + kc * 64;
        const bf16* ws = Wt + (size_t)c0 * 512 + kc * 64;
        #pragma unroll
        for (int c = 0; c < 4; ++c) {
            const int row = c * 32 + srow;
            gl_lds16(xs + (size_t)row * 512 + skb * 8, &Xl[buf][c * 2048 + sdst]);
        }
        #pragma unroll
        for (int c = 0; c < 4; ++c) {
            const int row = c * 32 + srow;
            gl_lds16(ws + (size_t)row * 512 + skb * 8, &Wl[buf][c * 2048 + sdst]);
        }
    };

    f32x4 acc[4][4] = {};

    stage(0, 0);

    for (int t = 0; t < 8; ++t) {
        const int buf = t & 1;
        if (t + 1 < 8) {
            stage(buf ^ 1, t + 1);
            // wait only for the PREVIOUS stage (8 older ops); new 8 in flight
            asm volatile("s_waitcnt vmcnt(8)" ::: "memory");
        } else {
            asm volatile("s_waitcnt vmcnt(0)" ::: "memory");
        }
        __builtin_amdgcn_s_barrier();           // B1: buf fully staged, published
        __builtin_amdgcn_sched_barrier(0);

        #pragma unroll
        for (int kk = 0; kk < 2; ++kk) {
            bf16x8 af[4], bfr[4];
            const int kb = kk * 4 + lhi;
            #pragma unroll
            for (int tt = 0; tt < 4; ++tt) {
                const int ra = wr * 64 + tt * 16 + lrow;
                af[tt] = *reinterpret_cast<const bf16x8*>(&Xl[buf][ra * 64 + ((kb ^ (ra & 7)) * 8)]);
            }
            #pragma unroll
            for (int tt = 0; tt < 4; ++tt) {
                const int rb = wc * 64 + tt * 16 + lrow;
                bfr[tt] = *reinterpret_cast<const bf16x8*>(&Wl[buf][rb * 64 + ((kb ^ (rb & 7)) * 8)]);
            }
            #pragma unroll
            for (int i = 0; i < 4; ++i)
                #pragma unroll
                for (int j = 0; j < 4; ++j)
                    acc[i][j] = mfma16(af[i], bfr[j], acc[i][j]);
        }

        // B2: reads of buf retired -> next iter may stage over buf (WAR)
        asm volatile("s_waitcnt lgkmcnt(0)" ::: "memory");
        __builtin_amdgcn_s_barrier();
        __builtin_amdgcn_sched_barrier(0);
    }

    #pragma unroll
    for (int i = 0; i < 4; ++i) {
        #pragma unroll
        for (int j = 0; j < 4; ++j) {
            const int col = c0 + wc * 64 + j * 16 + lrow;
            const float bb = bias[col];
            #pragma unroll
            for (int rg = 0; rg < 4; ++rg) {
                const int r = r0 + wr * 64 + i * 16 + lhi * 4 + rg;
                float y = acc[i][j][rg] + bb;
                y = y > 0.f ? y : 0.f;
                if (OMODE == 2) {
                    Yf[(size_t)r * 512 + col] = y;
                } else {
                    Y[(size_t)r * 512 + col] = (bf16)y;
                    if (OMODE == 1) {
                        const int bi = r >> 11, nn = r & 2047;
                        Yt[((size_t)bi * 512 + col) * 2048 + nn] = (bf16)y;
                    }
                }
            }
        }
    }
}

// ---------------- fused attention (R14-exact, 328us) ----------------
// scores = (Q K^T) * (-A); att = softmax(scores); O = att @ V + V  (bf16 out)
// max==0 softmax: q,k>=0 and A in [0,1) => scores<=0 => p = exp(x) directly,
// l accumulated per-lane, reduced once at epilogue. KVBLK=128 (16 iters).
// K SINGLE-buffered (128KB LDS), staged for it+1 right after B1 (WAR-safe:
// B1's lgkm(0) retires all K reads); completion for next iter via in-order
// vmcnt (vf issued after stage, waited in PV) + lgkm-only B2.
__global__ __launch_bounds__(512, 1)
void attn_kernel(const bf16* __restrict__ Q, const bf16* __restrict__ K,
                 const bf16* __restrict__ Vt, const bf16* __restrict__ V,
                 const float* __restrict__ A, bf16* __restrict__ O)
{
    __shared__ bf16 K_lds[128 * 512];     // 128KB, XOR-swizzled rows, single buffer
    __shared__ bf16 P_lds[64 * 144];      // 18KB, stride 144 (288B rows)
    __shared__ float sump_lds[2][64];     // per-strip l partials (epilogue only)

    const int tid = threadIdx.x;
    const int lane = tid & 63, wid = tid >> 6;
    const int wr = wid >> 1, wc = wid & 1;
    const int lrow = lane & 15, lhi = lane >> 4;

    // XCD x handles batches {2x, 2x+1}
    const int id = blockIdx.x;
    const int xcd = id & 7, j = id >> 3;
    const int bb = 2 * xcd + (j >> 5);
    const int n0 = (j & 31) * 64;
    const int srow_base = wr * 16 + lhi * 4;

    const bf16* Kbase  = K + (size_t)bb * SEQ * DH;
    const bf16* Vtbase = Vt + (size_t)bb * DH * SEQ;

    // stage K[0]: 128 rows, 16 per wave
    #pragma unroll
    for (int c = 0; c < 16; ++c) {
        const int row = wid * 16 + c;
        gl_lds16(Kbase + (size_t)row * DH + ((lane ^ (row & 7)) * 8), &K_lds[row * 512]);
    }

    // Q resident: rows n0 + wr*16 + lrow (wc pair loads same rows). 64 VGPR.
    bf16x8 qf[16];
    {
        const bf16* qp = Q + (size_t)(bb * SEQ + n0 + wr * 16 + lrow) * DH + lhi * 8;
        #pragma unroll
        for (int kk = 0; kk < 16; ++kk)
            qf[kk] = *reinterpret_cast<const bf16x8*>(qp + kk * 32);
    }

    float l_part[4] = {};      // per-lane denominator partials (rows srow_base+rg)
    f32x4 acc[4][4] = {};      // [q-row-tile][h-tile of this wave's 64-col slice]

    __syncthreads();  // K[0] drained + published

    for (int it = 0; it < 16; ++it) {
        const int m0 = it * 128;

        // A for this iter (consumed after QK^T, ~1200cy cover). 16 loads.
        float av[16];  // [sc*4 + rg]
        {
            const float* ap = A + ((size_t)bb * SEQ + n0 + srow_base) * SEQ + m0 + wc * 64 + lrow;
            #pragma unroll
            for (int sc = 0; sc < 4; ++sc)
                #pragma unroll
                for (int rg = 0; rg < 4; ++rg)
                    av[sc * 4 + rg] = ap[(size_t)rg * SEQ + sc * 16];
        }

        // ---- QK^T: S[16 rows x 64-col strip] from K_lds (4 indep chains) ----
        f32x4 s[4] = {};
        {
            #pragma unroll
            for (int kk = 0; kk < 16; ++kk) {
                const int ks = kk * 4 + lhi;
                #pragma unroll
                for (int sc = 0; sc < 4; ++sc) {
                    const int kr = wc * 64 + sc * 16 + lrow;
                    bf16x8 kf = *reinterpret_cast<const bf16x8*>(
                        &K_lds[kr * 512 + ((ks ^ (kr & 7)) * 8)]);
                    s[sc] = mfma16(qf[kk], kf, s[sc]);
                }
            }
        }

        // ---- p = exp(score * -A) (max==0); P -> LDS; l accumulate ----
        #pragma unroll
        for (int sc = 0; sc < 4; ++sc) {
            #pragma unroll
            for (int rg = 0; rg < 4; ++rg) {
                const float p = __expf(s[sc][rg] * (-av[sc * 4 + rg]));
                const int row = srow_base + rg;
                P_lds[row * 144 + wc * 64 + sc * 16 + lrow] = (bf16)p;
                l_part[rg] += p;
            }
        }

        // B1: lgkm-only — P writes + K reads retired; VMEM stays in flight
        asm volatile("s_waitcnt lgkmcnt(0)" ::: "memory");
        __builtin_amdgcn_s_barrier();
        __builtin_amdgcn_sched_barrier(0);

        // stage K[it+1] into the SAME buffer (WAR-safe: all K reads retired at
        // B1). Completion: vf loads below are issued AFTER these; PV's vf wait
        // (in-order vmcnt) forces stage completion; B2 publishes block-wide.
        if (it + 1 < 16) {
            #pragma unroll
            for (int c = 0; c < 16; ++c) {
                const int row = wid * 16 + c;
                gl_lds16(Kbase + (size_t)(m0 + 128 + row) * DH + ((lane ^ (row & 7)) * 8),
                         &K_lds[row * 512]);
            }
        }

        // ---- PV: P (LDS) x Vt (JIT regs, per-kc double-buffer) ----
        {
            const bf16* vp = Vtbase + (size_t)(wid * 64 + lrow) * SEQ + m0 + lhi * 8;
            bf16x8 vfk[2][4];
            #pragma unroll
            for (int ht = 0; ht < 4; ++ht)
                vfk[0][ht] = *reinterpret_cast<const bf16x8*>(vp + (size_t)(ht * 16) * SEQ);
            #pragma unroll
            for (int kc = 0; kc < 4; ++kc) {
                if (kc + 1 < 4) {
                    #pragma unroll
                    for (int ht = 0; ht < 4; ++ht)
                        vfk[(kc + 1) & 1][ht] = *reinterpret_cast<const bf16x8*>(
                            vp + (size_t)(ht * 16) * SEQ + (kc + 1) * 32);
                }
                #pragma unroll
                for (int t = 0; t < 4; ++t) {
                    const bf16x8 pf = *reinterpret_cast<const bf16x8*>(
                        &P_lds[(t * 16 + lrow) * 144 + kc * 32 + lhi * 8]);
                    #pragma unroll
                    for (int ht = 0; ht < 4; ++ht)
                        acc[t][ht] = mfma16(pf, vfk[kc & 1][ht], acc[t][ht]);
                }
            }
        }

        // B2: lgkm-only — P reads retired (WAR for next writes); K[it+1] stage
        // complete per-wave (via vf in-order waits) -> published block-wide.
        asm volatile("s_waitcnt lgkmcnt(0)" ::: "memory");
        __builtin_amdgcn_s_barrier();
        __builtin_amdgcn_sched_barrier(0);
    }

    // ---- epilogue: reduce l over the 16 lrow lanes per strip, combine strips ----
    #pragma unroll
    for (int rg = 0; rg < 4; ++rg) {
        float sv = l_part[rg];
        sv += __shfl_xor(sv, 1);
        sv += __shfl_xor(sv, 2);
        sv += __shfl_xor(sv, 4);
        sv += __shfl_xor(sv, 8);
        if (lrow == 0) sump_lds[wc][srow_base + rg] = sv;
    }
    __syncthreads();

    // ---- /l, +V, store ----
    #pragma unroll
    for (int t = 0; t < 4; ++t) {
        #pragma unroll
        for (int rg = 0; rg < 4; ++rg) {
            const int row = t * 16 + lhi * 4 + rg;
            const float inv = 1.f / (sump_lds[0][row] + sump_lds[1][row]);
            const size_t rbase = (size_t)(bb * SEQ + n0 + row) * DH;
            #pragma unroll
            for (int ht = 0; ht < 4; ++ht) {
                const int col = wid * 64 + ht * 16 + lrow;
                const float vv = (float)V[rbase + col];
                O[rbase + col] = (bf16)(acc[t][ht][rg] * inv + vv);
            }
        }
    }
}

extern "C" void kernel_launch(void* const* d_in, const int* in_sizes, int n_in,
                              void* d_out, int out_size, void* d_ws, size_t ws_size,
                              hipStream_t stream) {
    const float* A    = (const float*)d_in[0];
    const float* h    = (const float*)d_in[1];
    const float* Wv1  = (const float*)d_in[2];
    const float* bv1  = (const float*)d_in[3];
    const float* Wv2  = (const float*)d_in[4];
    const float* bv2  = (const float*)d_in[5];
    const float* Wk   = (const float*)d_in[6];   // NOTE: Wk before Wq in dict order
    const float* bk   = (const float*)d_in[7];
    const float* Wq   = (const float*)d_in[8];
    const float* bq   = (const float*)d_in[9];
    const float* Wout = (const float*)d_in[10];
    const float* bout = (const float*)d_in[11];
    float* out = (float*)d_out;

    char* ws = (char*)d_ws;
    const size_t SZ = (size_t)ROWS * 512 * sizeof(bf16);  // 33.5 MB
    bf16* hb   = (bf16*)(ws + 0 * SZ);  // h in bf16; later reused as attention output
    bf16* tq   = (bf16*)(ws + 1 * SZ);  // t = relu(h@Wv1), later overwritten with q
    bf16* kb   = (bf16*)(ws + 2 * SZ);
    bf16* vb   = (bf16*)(ws + 3 * SZ);
    bf16* vtb  = (bf16*)(ws + 4 * SZ);  // v transposed: [B][H][N]
    bf16* wbase = (bf16*)(ws + 5 * SZ); // 5 x 512KB bf16 weights
    bf16* Wv1t  = wbase + 0 * 262144;
    bf16* Wv2t  = wbase + 1 * 262144;
    bf16* Wqt   = wbase + 2 * 262144;
    bf16* Wkt   = wbase + 3 * 262144;
    bf16* Woutt = wbase + 4 * 262144;
    bf16* ob = hb;  // attention output aliases hb (hb dead after k projection)

    cvt_bf16_kernel<<<4096, 256, 0, stream>>>(h, hb, ROWS * 512 / 4);
    cvt_wT5_kernel<<<dim3(1024, 5), 256, 0, stream>>>(Wv1, Wv2, Wq, Wk, Wout, wbase);

    dim3 gg(ROWS / 128, 512 / 128);  // (256, 4)
    gemm_relu_kernel<0><<<gg, 256, 0, stream>>>(hb, Wv1t, bv1, tq, nullptr, nullptr);  // t
    gemm_relu_kernel<1><<<gg, 256, 0, stream>>>(tq, Wv2t, bv2, vb, vtb, nullptr);      // v + vT
    gemm_relu_kernel<0><<<gg, 256, 0, stream>>>(hb, Wqt, bq, tq, nullptr, nullptr);    // q (over t)
    gemm_relu_kernel<0><<<gg, 256, 0, stream>>>(hb, Wkt, bk, kb, nullptr, nullptr);    // k

    attn_kernel<<<dim3(512), 512, 0, stream>>>(tq, kb, vtb, vb, A, ob);

    gemm_relu_kernel<2><<<gg, 256, 0, stream>>>(ob, Woutt, bout, nullptr, nullptr, out);
}

// Round 18
// 479.914 us; speedup vs baseline: 1.2990x; 1.0582x over previous
//
#include <hip/hip_runtime.h>

typedef __bf16 bf16;
typedef bf16 bf16x4 __attribute__((ext_vector_type(4)));
typedef bf16 bf16x8 __attribute__((ext_vector_type(8)));
typedef float f32x4 __attribute__((ext_vector_type(4)));

static constexpr int BATCH = 16;
static constexpr int SEQ   = 2048;  // N
static constexpr int DH    = 512;   // H (== M)
static constexpr int ROWS  = BATCH * SEQ;  // 32768

__device__ __forceinline__ f32x4 mfma16(bf16x8 a, bf16x8 b, f32x4 c) {
    return __builtin_amdgcn_mfma_f32_16x16x32_bf16(a, b, c, 0, 0, 0);
}

// async global->LDS, 16B per lane. dst must be wave-uniform base (HW adds lane*16).
__device__ __forceinline__ void gl_lds16(const void* g, void* l) {
    __builtin_amdgcn_global_load_lds((const __attribute__((address_space(1))) void*)g,
                                     (__attribute__((address_space(3))) void*)l, 16, 0, 0);
}

// ---------------- fp32 -> bf16 (vectorized) ----------------
__global__ void cvt_bf16_kernel(const float* __restrict__ in, bf16* __restrict__ out, int n4) {
    int i = blockIdx.x * blockDim.x + threadIdx.x;
    const int stride = gridDim.x * blockDim.x;
    for (; i < n4; i += stride) {
        f32x4 f = *reinterpret_cast<const f32x4*>(in + (size_t)i * 4);
        bf16x4 o;
        o[0] = (bf16)f[0]; o[1] = (bf16)f[1]; o[2] = (bf16)f[2]; o[3] = (bf16)f[3];
        *reinterpret_cast<bf16x4*>(out + (size_t)i * 4) = o;
    }
}

// -------- all 5 weights [K=512][N=512] fp32 -> [N][K] bf16, one launch --------
__global__ void cvt_wT5_kernel(const float* __restrict__ w0, const float* __restrict__ w1,
                               const float* __restrict__ w2, const float* __restrict__ w3,
                               const float* __restrict__ w4, bf16* __restrict__ out) {
    const int t = blockIdx.y;
    const float* in = (t == 0) ? w0 : (t == 1) ? w1 : (t == 2) ? w2 : (t == 3) ? w3 : w4;
    int idx = blockIdx.x * 256 + threadIdx.x;  // idx = n*512 + k
    int n = idx >> 9, k = idx & 511;
    out[t * 262144 + idx] = (bf16)in[k * 512 + n];
}

// ---------------- GEMM: Y = relu(X[R,512] @ W[512,512] + b), LDS staged ----
// R18: XCD-coherent 1D grid swizzle. id -> (row=(id>>5)*8+(id&7), col=(id>>3)&3):
// the 4 column-tiles of one X row-panel share id&7 (same XCD) and are within
// 32 consecutive ids (co-resident) -> X panel is fetched from HBM once and
// L2-hits for the other 3 tiles. Was: grid (256,4), X fetched 4x = 134 MB.
template <int OMODE>
__global__ __launch_bounds__(256, 2)
void gemm_relu_kernel(const bf16* __restrict__ X, const bf16* __restrict__ Wt,
                      const float* __restrict__ bias,
                      bf16* __restrict__ Y, bf16* __restrict__ Yt,
                      float* __restrict__ Yf)
{
    __shared__ bf16 Xl[2][128 * 64];
    __shared__ bf16 Wl[2][128 * 64];

    const int tid = threadIdx.x;
    const int lane = tid & 63, wid = tid >> 6;
    const int wr = wid >> 1, wc = wid & 1;
    const int id = blockIdx.x;
    const int r0 = (((id >> 5) << 3) + (id & 7)) * 128;  // row-panel
    const int c0 = ((id >> 3) & 3) * 128;                // col-tile
    const int lrow = lane & 15, lhi = lane >> 4;

    const int srow = tid >> 3;                // 0..31 within call
    const int skb  = (tid & 7) ^ (srow & 7);  // pre-swizzled source block
    const int sdst = wid * 512;               // this wave's 1KB chunk

    auto stage = [&](int buf, int kc) {       // 8 gl_lds16 per thread
        const bf16* xs = X + (size_t)r0 * 512 + kc * 64;
        const bf16* ws = Wt + (size_t)c0 * 512 + kc * 64;
        #pragma unroll
        for (int c = 0; c < 4; ++c) {
            const int row = c * 32 + srow;
            gl_lds16(xs + (size_t)row * 512 + skb * 8, &Xl[buf][c * 2048 + sdst]);
        }
        #pragma unroll
        for (int c = 0; c < 4; ++c) {
            const int row = c * 32 + srow;
            gl_lds16(ws + (size_t)row * 512 + skb * 8, &Wl[buf][c * 2048 + sdst]);
        }
    };

    f32x4 acc[4][4] = {};

    stage(0, 0);

    for (int t = 0; t < 8; ++t) {
        const int buf = t & 1;
        if (t + 1 < 8) {
            stage(buf ^ 1, t + 1);
            // wait only for the PREVIOUS stage (8 older ops); new 8 in flight
            asm volatile("s_waitcnt vmcnt(8)" ::: "memory");
        } else {
            asm volatile("s_waitcnt vmcnt(0)" ::: "memory");
        }
        __builtin_amdgcn_s_barrier();           // B1: buf fully staged, published
        __builtin_amdgcn_sched_barrier(0);

        #pragma unroll
        for (int kk = 0; kk < 2; ++kk) {
            bf16x8 af[4], bfr[4];
            const int kb = kk * 4 + lhi;
            #pragma unroll
            for (int tt = 0; tt < 4; ++tt) {
                const int ra = wr * 64 + tt * 16 + lrow;
                af[tt] = *reinterpret_cast<const bf16x8*>(&Xl[buf][ra * 64 + ((kb ^ (ra & 7)) * 8)]);
            }
            #pragma unroll
            for (int tt = 0; tt < 4; ++tt) {
                const int rb = wc * 64 + tt * 16 + lrow;
                bfr[tt] = *reinterpret_cast<const bf16x8*>(&Wl[buf][rb * 64 + ((kb ^ (rb & 7)) * 8)]);
            }
            #pragma unroll
            for (int i = 0; i < 4; ++i)
                #pragma unroll
                for (int j = 0; j < 4; ++j)
                    acc[i][j] = mfma16(af[i], bfr[j], acc[i][j]);
        }

        // B2: reads of buf retired -> next iter may stage over buf (WAR)
        asm volatile("s_waitcnt lgkmcnt(0)" ::: "memory");
        __builtin_amdgcn_s_barrier();
        __builtin_amdgcn_sched_barrier(0);
    }

    #pragma unroll
    for (int i = 0; i < 4; ++i) {
        #pragma unroll
        for (int j = 0; j < 4; ++j) {
            const int col = c0 + wc * 64 + j * 16 + lrow;
            const float bb = bias[col];
            #pragma unroll
            for (int rg = 0; rg < 4; ++rg) {
                const int r = r0 + wr * 64 + i * 16 + lhi * 4 + rg;
                float y = acc[i][j][rg] + bb;
                y = y > 0.f ? y : 0.f;
                if (OMODE == 2) {
                    Yf[(size_t)r * 512 + col] = y;
                } else {
                    Y[(size_t)r * 512 + col] = (bf16)y;
                    if (OMODE == 1) {
                        const int bi = r >> 11, nn = r & 2047;
                        Yt[((size_t)bi * 512 + col) * 2048 + nn] = (bf16)y;
                    }
                }
            }
        }
    }
}

// ---------------- fused attention (R14-exact, ~330us) ----------------
// scores = (Q K^T) * (-A); att = softmax(scores); O = att @ V + V  (bf16 out)
// max==0 softmax: q,k>=0 and A in [0,1) => scores<=0 => p = exp(x) directly,
// l accumulated per-lane, reduced once at epilogue. KVBLK=128 (16 iters).
// K SINGLE-buffered (128KB LDS), staged for it+1 right after B1 (WAR-safe:
// B1's lgkm(0) retires all K reads); completion for next iter via in-order
// vmcnt (vf issued after stage, waited in PV) + lgkm-only B2.
__global__ __launch_bounds__(512, 1)
void attn_kernel(const bf16* __restrict__ Q, const bf16* __restrict__ K,
                 const bf16* __restrict__ Vt, const bf16* __restrict__ V,
                 const float* __restrict__ A, bf16* __restrict__ O)
{
    __shared__ bf16 K_lds[128 * 512];     // 128KB, XOR-swizzled rows, single buffer
    __shared__ bf16 P_lds[64 * 144];      // 18KB, stride 144 (288B rows)
    __shared__ float sump_lds[2][64];     // per-strip l partials (epilogue only)

    const int tid = threadIdx.x;
    const int lane = tid & 63, wid = tid >> 6;
    const int wr = wid >> 1, wc = wid & 1;
    const int lrow = lane & 15, lhi = lane >> 4;

    // XCD x handles batches {2x, 2x+1}
    const int id = blockIdx.x;
    const int xcd = id & 7, j = id >> 3;
    const int bb = 2 * xcd + (j >> 5);
    const int n0 = (j & 31) * 64;
    const int srow_base = wr * 16 + lhi * 4;

    const bf16* Kbase  = K + (size_t)bb * SEQ * DH;
    const bf16* Vtbase = Vt + (size_t)bb * DH * SEQ;

    // stage K[0]: 128 rows, 16 per wave
    #pragma unroll
    for (int c = 0; c < 16; ++c) {
        const int row = wid * 16 + c;
        gl_lds16(Kbase + (size_t)row * DH + ((lane ^ (row & 7)) * 8), &K_lds[row * 512]);
    }

    // Q resident: rows n0 + wr*16 + lrow (wc pair loads same rows). 64 VGPR.
    bf16x8 qf[16];
    {
        const bf16* qp = Q + (size_t)(bb * SEQ + n0 + wr * 16 + lrow) * DH + lhi * 8;
        #pragma unroll
        for (int kk = 0; kk < 16; ++kk)
            qf[kk] = *reinterpret_cast<const bf16x8*>(qp + kk * 32);
    }

    float l_part[4] = {};      // per-lane denominator partials (rows srow_base+rg)
    f32x4 acc[4][4] = {};      // [q-row-tile][h-tile of this wave's 64-col slice]

    __syncthreads();  // K[0] drained + published

    for (int it = 0; it < 16; ++it) {
        const int m0 = it * 128;

        // A for this iter (consumed after QK^T, ~1200cy cover). 16 loads.
        float av[16];  // [sc*4 + rg]
        {
            const float* ap = A + ((size_t)bb * SEQ + n0 + srow_base) * SEQ + m0 + wc * 64 + lrow;
            #pragma unroll
            for (int sc = 0; sc < 4; ++sc)
                #pragma unroll
                for (int rg = 0; rg < 4; ++rg)
                    av[sc * 4 + rg] = ap[(size_t)rg * SEQ + sc * 16];
        }

        // ---- QK^T: S[16 rows x 64-col strip] from K_lds (4 indep chains) ----
        f32x4 s[4] = {};
        {
            #pragma unroll
            for (int kk = 0; kk < 16; ++kk) {
                const int ks = kk * 4 + lhi;
                #pragma unroll
                for (int sc = 0; sc < 4; ++sc) {
                    const int kr = wc * 64 + sc * 16 + lrow;
                    bf16x8 kf = *reinterpret_cast<const bf16x8*>(
                        &K_lds[kr * 512 + ((ks ^ (kr & 7)) * 8)]);
                    s[sc] = mfma16(qf[kk], kf, s[sc]);
                }
            }
        }

        // ---- p = exp(score * -A) (max==0); P -> LDS; l accumulate ----
        #pragma unroll
        for (int sc = 0; sc < 4; ++sc) {
            #pragma unroll
            for (int rg = 0; rg < 4; ++rg) {
                const float p = __expf(s[sc][rg] * (-av[sc * 4 + rg]));
                const int row = srow_base + rg;
                P_lds[row * 144 + wc * 64 + sc * 16 + lrow] = (bf16)p;
                l_part[rg] += p;
            }
        }

        // B1: lgkm-only — P writes + K reads retired; VMEM stays in flight
        asm volatile("s_waitcnt lgkmcnt(0)" ::: "memory");
        __builtin_amdgcn_s_barrier();
        __builtin_amdgcn_sched_barrier(0);

        // stage K[it+1] into the SAME buffer (WAR-safe: all K reads retired at
        // B1). Completion: vf loads below are issued AFTER these; PV's vf wait
        // (in-order vmcnt) forces stage completion; B2 publishes block-wide.
        if (it + 1 < 16) {
            #pragma unroll
            for (int c = 0; c < 16; ++c) {
                const int row = wid * 16 + c;
                gl_lds16(Kbase + (size_t)(m0 + 128 + row) * DH + ((lane ^ (row & 7)) * 8),
                         &K_lds[row * 512]);
            }
        }

        // ---- PV: P (LDS) x Vt (JIT regs, per-kc double-buffer) ----
        {
            const bf16* vp = Vtbase + (size_t)(wid * 64 + lrow) * SEQ + m0 + lhi * 8;
            bf16x8 vfk[2][4];
            #pragma unroll
            for (int ht = 0; ht < 4; ++ht)
                vfk[0][ht] = *reinterpret_cast<const bf16x8*>(vp + (size_t)(ht * 16) * SEQ);
            #pragma unroll
            for (int kc = 0; kc < 4; ++kc) {
                if (kc + 1 < 4) {
                    #pragma unroll
                    for (int ht = 0; ht < 4; ++ht)
                        vfk[(kc + 1) & 1][ht] = *reinterpret_cast<const bf16x8*>(
                            vp + (size_t)(ht * 16) * SEQ + (kc + 1) * 32);
                }
                #pragma unroll
                for (int t = 0; t < 4; ++t) {
                    const bf16x8 pf = *reinterpret_cast<const bf16x8*>(
                        &P_lds[(t * 16 + lrow) * 144 + kc * 32 + lhi * 8]);
                    #pragma unroll
                    for (int ht = 0; ht < 4; ++ht)
                        acc[t][ht] = mfma16(pf, vfk[kc & 1][ht], acc[t][ht]);
                }
            }
        }

        // B2: lgkm-only — P reads retired (WAR for next writes); K[it+1] stage
        // complete per-wave (via vf in-order waits) -> published block-wide.
        asm volatile("s_waitcnt lgkmcnt(0)" ::: "memory");
        __builtin_amdgcn_s_barrier();
        __builtin_amdgcn_sched_barrier(0);
    }

    // ---- epilogue: reduce l over the 16 lrow lanes per strip, combine strips ----
    #pragma unroll
    for (int rg = 0; rg < 4; ++rg) {
        float sv = l_part[rg];
        sv += __shfl_xor(sv, 1);
        sv += __shfl_xor(sv, 2);
        sv += __shfl_xor(sv, 4);
        sv += __shfl_xor(sv, 8);
        if (lrow == 0) sump_lds[wc][srow_base + rg] = sv;
    }
    __syncthreads();

    // ---- /l, +V, store ----
    #pragma unroll
    for (int t = 0; t < 4; ++t) {
        #pragma unroll
        for (int rg = 0; rg < 4; ++rg) {
            const int row = t * 16 + lhi * 4 + rg;
            const float inv = 1.f / (sump_lds[0][row] + sump_lds[1][row]);
            const size_t rbase = (size_t)(bb * SEQ + n0 + row) * DH;
            #pragma unroll
            for (int ht = 0; ht < 4; ++ht) {
                const int col = wid * 64 + ht * 16 + lrow;
                const float vv = (float)V[rbase + col];
                O[rbase + col] = (bf16)(acc[t][ht][rg] * inv + vv);
            }
        }
    }
}

extern "C" void kernel_launch(void* const* d_in, const int* in_sizes, int n_in,
                              void* d_out, int out_size, void* d_ws, size_t ws_size,
                              hipStream_t stream) {
    const float* A    = (const float*)d_in[0];
    const float* h    = (const float*)d_in[1];
    const float* Wv1  = (const float*)d_in[2];
    const float* bv1  = (const float*)d_in[3];
    const float* Wv2  = (const float*)d_in[4];
    const float* bv2  = (const float*)d_in[5];
    const float* Wk   = (const float*)d_in[6];   // NOTE: Wk before Wq in dict order
    const float* bk   = (const float*)d_in[7];
    const float* Wq   = (const float*)d_in[8];
    const float* bq   = (const float*)d_in[9];
    const float* Wout = (const float*)d_in[10];
    const float* bout = (const float*)d_in[11];
    float* out = (float*)d_out;

    char* ws = (char*)d_ws;
    const size_t SZ = (size_t)ROWS * 512 * sizeof(bf16);  // 33.5 MB
    bf16* hb   = (bf16*)(ws + 0 * SZ);  // h in bf16; later reused as attention output
    bf16* tq   = (bf16*)(ws + 1 * SZ);  // t = relu(h@Wv1), later overwritten with q
    bf16* kb   = (bf16*)(ws + 2 * SZ);
    bf16* vb   = (bf16*)(ws + 3 * SZ);
    bf16* vtb  = (bf16*)(ws + 4 * SZ);  // v transposed: [B][H][N]
    bf16* wbase = (bf16*)(ws + 5 * SZ); // 5 x 512KB bf16 weights
    bf16* Wv1t  = wbase + 0 * 262144;
    bf16* Wv2t  = wbase + 1 * 262144;
    bf16* Wqt   = wbase + 2 * 262144;
    bf16* Wkt   = wbase + 3 * 262144;
    bf16* Woutt = wbase + 4 * 262144;
    bf16* ob = hb;  // attention output aliases hb (hb dead after k projection)

    cvt_bf16_kernel<<<4096, 256, 0, stream>>>(h, hb, ROWS * 512 / 4);
    cvt_wT5_kernel<<<dim3(1024, 5), 256, 0, stream>>>(Wv1, Wv2, Wq, Wk, Wout, wbase);

    gemm_relu_kernel<0><<<1024, 256, 0, stream>>>(hb, Wv1t, bv1, tq, nullptr, nullptr);  // t
    gemm_relu_kernel<1><<<1024, 256, 0, stream>>>(tq, Wv2t, bv2, vb, vtb, nullptr);      // v + vT
    gemm_relu_kernel<0><<<1024, 256, 0, stream>>>(hb, Wqt, bq, tq, nullptr, nullptr);    // q (over t)
    gemm_relu_kernel<0><<<1024, 256, 0, stream>>>(hb, Wkt, bk, kb, nullptr, nullptr);    // k

    attn_kernel<<<dim3(512), 512, 0, stream>>>(tq, kb, vtb, vb, A, ob);

    gemm_relu_kernel<2><<<1024, 256, 0, stream>>>(ob, Woutt, bout, nullptr, nullptr, out);
}

// Round 19
// 450.074 us; speedup vs baseline: 1.3852x; 1.0663x over previous
//
#include <hip/hip_runtime.h>

typedef __bf16 bf16;
typedef bf16 bf16x4 __attribute__((ext_vector_type(4)));
typedef bf16 bf16x8 __attribute__((ext_vector_type(8)));
typedef float f32x4 __attribute__((ext_vector_type(4)));

static constexpr int BATCH = 16;
static constexpr int SEQ   = 2048;  // N
static constexpr int DH    = 512;   // H (== M)
static constexpr int ROWS  = BATCH * SEQ;  // 32768

__device__ __forceinline__ f32x4 mfma16(bf16x8 a, bf16x8 b, f32x4 c) {
    return __builtin_amdgcn_mfma_f32_16x16x32_bf16(a, b, c, 0, 0, 0);
}

// async global->LDS, 16B per lane. dst must be wave-uniform base (HW adds lane*16).
__device__ __forceinline__ void gl_lds16(const void* g, void* l) {
    __builtin_amdgcn_global_load_lds((const __attribute__((address_space(1))) void*)g,
                                     (__attribute__((address_space(3))) void*)l, 16, 0, 0);
}

// -------- fused conversions: h fp32->bf16 + 5 weights fp32->[N][K] bf16 --------
// blocks 0..4095: h (grid-stride f32x4); blocks 4096..9215: weight transpose.
__global__ void cvt_all_kernel(const float* __restrict__ h,
                               const float* __restrict__ w0, const float* __restrict__ w1,
                               const float* __restrict__ w2, const float* __restrict__ w3,
                               const float* __restrict__ w4,
                               bf16* __restrict__ hb, bf16* __restrict__ wout) {
    const int b = blockIdx.x;
    if (b < 4096) {
        const int n4 = ROWS * 512 / 4;
        int i = b * 256 + threadIdx.x;
        const int stride = 4096 * 256;
        for (; i < n4; i += stride) {
            f32x4 f = *reinterpret_cast<const f32x4*>(h + (size_t)i * 4);
            bf16x4 o;
            o[0] = (bf16)f[0]; o[1] = (bf16)f[1]; o[2] = (bf16)f[2]; o[3] = (bf16)f[3];
            *reinterpret_cast<bf16x4*>(hb + (size_t)i * 4) = o;
        }
    } else {
        const int bb = b - 4096;
        const int t = bb >> 10;
        const float* in = (t == 0) ? w0 : (t == 1) ? w1 : (t == 2) ? w2 : (t == 3) ? w3 : w4;
        int idx = (bb & 1023) * 256 + threadIdx.x;  // idx = n*512 + k
        int n = idx >> 9, k = idx & 511;
        wout[t * 262144 + idx] = (bf16)in[k * 512 + n];
    }
}

// ---------------- GEMM: Y = relu(X[R,512] @ W[512,512] + b), LDS staged ----
// R18: XCD-coherent 1D grid swizzle. id -> (row=(id>>5)*8+(id&7), col=(id>>3)&3):
// the 4 column-tiles of one X row-panel share id&7 (same XCD) and are within
// 32 consecutive ids (co-resident) -> X panel fetched from HBM once, L2-hits after.
template <int OMODE>
__global__ __launch_bounds__(256, 2)
void gemm_relu_kernel(const bf16* __restrict__ X, const bf16* __restrict__ Wt,
                      const float* __restrict__ bias,
                      bf16* __restrict__ Y, bf16* __restrict__ Yt,
                      float* __restrict__ Yf)
{
    __shared__ bf16 Xl[2][128 * 64];
    __shared__ bf16 Wl[2][128 * 64];

    const int tid = threadIdx.x;
    const int lane = tid & 63, wid = tid >> 6;
    const int wr = wid >> 1, wc = wid & 1;
    const int id = blockIdx.x;
    const int r0 = (((id >> 5) << 3) + (id & 7)) * 128;  // row-panel
    const int c0 = ((id >> 3) & 3) * 128;                // col-tile
    const int lrow = lane & 15, lhi = lane >> 4;

    const int srow = tid >> 3;                // 0..31 within call
    const int skb  = (tid & 7) ^ (srow & 7);  // pre-swizzled source block
    const int sdst = wid * 512;               // this wave's 1KB chunk

    auto stage = [&](int buf, int kc) {       // 8 gl_lds16 per thread
        const bf16* xs = X + (size_t)r0 * 512 + kc * 64;
        const bf16* ws = Wt + (size_t)c0 * 512 + kc * 64;
        #pragma unroll
        for (int c = 0; c < 4; ++c) {
            const int row = c * 32 + srow;
            gl_lds16(xs + (size_t)row * 512 + skb * 8, &Xl[buf][c * 2048 + sdst]);
        }
        #pragma unroll
        for (int c = 0; c < 4; ++c) {
            const int row = c * 32 + srow;
            gl_lds16(ws + (size_t)row * 512 + skb * 8, &Wl[buf][c * 2048 + sdst]);
        }
    };

    f32x4 acc[4][4] = {};

    stage(0, 0);

    for (int t = 0; t < 8; ++t) {
        const int buf = t & 1;
        if (t + 1 < 8) {
            stage(buf ^ 1, t + 1);
            asm volatile("s_waitcnt vmcnt(8)" ::: "memory");
        } else {
            asm volatile("s_waitcnt vmcnt(0)" ::: "memory");
        }
        __builtin_amdgcn_s_barrier();           // B1: buf fully staged, published
        __builtin_amdgcn_sched_barrier(0);

        #pragma unroll
        for (int kk = 0; kk < 2; ++kk) {
            bf16x8 af[4], bfr[4];
            const int kb = kk * 4 + lhi;
            #pragma unroll
            for (int tt = 0; tt < 4; ++tt) {
                const int ra = wr * 64 + tt * 16 + lrow;
                af[tt] = *reinterpret_cast<const bf16x8*>(&Xl[buf][ra * 64 + ((kb ^ (ra & 7)) * 8)]);
            }
            #pragma unroll
            for (int tt = 0; tt < 4; ++tt) {
                const int rb = wc * 64 + tt * 16 + lrow;
                bfr[tt] = *reinterpret_cast<const bf16x8*>(&Wl[buf][rb * 64 + ((kb ^ (rb & 7)) * 8)]);
            }
            #pragma unroll
            for (int i = 0; i < 4; ++i)
                #pragma unroll
                for (int j = 0; j < 4; ++j)
                    acc[i][j] = mfma16(af[i], bfr[j], acc[i][j]);
        }

        // B2: reads of buf retired -> next iter may stage over buf (WAR)
        asm volatile("s_waitcnt lgkmcnt(0)" ::: "memory");
        __builtin_amdgcn_s_barrier();
        __builtin_amdgcn_sched_barrier(0);
    }

    #pragma unroll
    for (int i = 0; i < 4; ++i) {
        #pragma unroll
        for (int j = 0; j < 4; ++j) {
            const int col = c0 + wc * 64 + j * 16 + lrow;
            const float bb = bias[col];
            #pragma unroll
            for (int rg = 0; rg < 4; ++rg) {
                const int r = r0 + wr * 64 + i * 16 + lhi * 4 + rg;
                float y = acc[i][j][rg] + bb;
                y = y > 0.f ? y : 0.f;
                if (OMODE == 2) {
                    Yf[(size_t)r * 512 + col] = y;
                } else {
                    Y[(size_t)r * 512 + col] = (bf16)y;
                    if (OMODE == 1) {
                        const int bi = r >> 11, nn = r & 2047;
                        Yt[((size_t)bi * 512 + col) * 2048 + nn] = (bf16)y;
                    }
                }
            }
        }
    }
}

// ---------------- fused attention ----------------
// max==0 softmax (q,k>=0, A in [0,1) => scores<=0): p = exp(x) directly,
// l per-lane, reduced once at epilogue. KVBLK=128 (16 iters). K single-buffered
// (128KB), staged after B1. R19: P_lds stride 128 + 16B-block XOR swizzle
// (was stride 144 = 288B == 32 mod 128 -> 4-way conflicts on pf reads/writes;
// now 2-way = free). s_setprio(1) around both MFMA clusters (T5).
__global__ __launch_bounds__(512, 1)
void attn_kernel(const bf16* __restrict__ Q, const bf16* __restrict__ K,
                 const bf16* __restrict__ Vt, const bf16* __restrict__ V,
                 const float* __restrict__ A, bf16* __restrict__ O)
{
    __shared__ bf16 K_lds[128 * 512];     // 128KB, XOR-swizzled rows, single buffer
    __shared__ bf16 P_lds[64 * 128];      // 16KB, stride 128, XOR-swizzled 16B blocks
    __shared__ float sump_lds[2][64];     // per-strip l partials (epilogue only)

    const int tid = threadIdx.x;
    const int lane = tid & 63, wid = tid >> 6;
    const int wr = wid >> 1, wc = wid & 1;
    const int lrow = lane & 15, lhi = lane >> 4;

    // XCD x handles batches {2x, 2x+1}
    const int id = blockIdx.x;
    const int xcd = id & 7, j = id >> 3;
    const int bb = 2 * xcd + (j >> 5);
    const int n0 = (j & 31) * 64;
    const int srow_base = wr * 16 + lhi * 4;

    const bf16* Kbase  = K + (size_t)bb * SEQ * DH;
    const bf16* Vtbase = Vt + (size_t)bb * DH * SEQ;

    // stage K[0]: 128 rows, 16 per wave
    #pragma unroll
    for (int c = 0; c < 16; ++c) {
        const int row = wid * 16 + c;
        gl_lds16(Kbase + (size_t)row * DH + ((lane ^ (row & 7)) * 8), &K_lds[row * 512]);
    }

    // Q resident: rows n0 + wr*16 + lrow (wc pair loads same rows). 64 VGPR.
    bf16x8 qf[16];
    {
        const bf16* qp = Q + (size_t)(bb * SEQ + n0 + wr * 16 + lrow) * DH + lhi * 8;
        #pragma unroll
        for (int kk = 0; kk < 16; ++kk)
            qf[kk] = *reinterpret_cast<const bf16x8*>(qp + kk * 32);
    }

    float l_part[4] = {};      // per-lane denominator partials (rows srow_base+rg)
    f32x4 acc[4][4] = {};      // [q-row-tile][h-tile of this wave's 64-col slice]

    __syncthreads();  // K[0] drained + published

    for (int it = 0; it < 16; ++it) {
        const int m0 = it * 128;

        // A for this iter (consumed after QK^T). 16 loads.
        float av[16];  // [sc*4 + rg]
        {
            const float* ap = A + ((size_t)bb * SEQ + n0 + srow_base) * SEQ + m0 + wc * 64 + lrow;
            #pragma unroll
            for (int sc = 0; sc < 4; ++sc)
                #pragma unroll
                for (int rg = 0; rg < 4; ++rg)
                    av[sc * 4 + rg] = ap[(size_t)rg * SEQ + sc * 16];
        }

        // ---- QK^T: S[16 rows x 64-col strip] from K_lds (4 indep chains) ----
        f32x4 s[4] = {};
        {
            __builtin_amdgcn_s_setprio(1);
            #pragma unroll
            for (int kk = 0; kk < 16; ++kk) {
                const int ks = kk * 4 + lhi;
                #pragma unroll
                for (int sc = 0; sc < 4; ++sc) {
                    const int kr = wc * 64 + sc * 16 + lrow;
                    bf16x8 kf = *reinterpret_cast<const bf16x8*>(
                        &K_lds[kr * 512 + ((ks ^ (kr & 7)) * 8)]);
                    s[sc] = mfma16(qf[kk], kf, s[sc]);
                }
            }
            __builtin_amdgcn_s_setprio(0);
        }

        // ---- p = exp(score * -A) (max==0); P -> LDS (swizzled); l accumulate ----
        #pragma unroll
        for (int sc = 0; sc < 4; ++sc) {
            #pragma unroll
            for (int rg = 0; rg < 4; ++rg) {
                const float p = __expf(s[sc][rg] * (-av[sc * 4 + rg]));
                const int row = srow_base + rg;
                const int blk = wc * 8 + sc * 2 + (lrow >> 3);   // col>>3
                P_lds[row * 128 + ((blk ^ (row & 7)) * 8) + (lrow & 7)] = (bf16)p;
                l_part[rg] += p;
            }
        }

        // B1: lgkm-only — P writes + K reads retired; VMEM stays in flight
        asm volatile("s_waitcnt lgkmcnt(0)" ::: "memory");
        __builtin_amdgcn_s_barrier();
        __builtin_amdgcn_sched_barrier(0);

        // stage K[it+1] into the SAME buffer (WAR-safe: all K reads retired at
        // B1). Completion: vf loads below issued AFTER these; PV's vf wait
        // (in-order vmcnt) forces stage completion; B2 publishes block-wide.
        if (it + 1 < 16) {
            #pragma unroll
            for (int c = 0; c < 16; ++c) {
                const int row = wid * 16 + c;
                gl_lds16(Kbase + (size_t)(m0 + 128 + row) * DH + ((lane ^ (row & 7)) * 8),
                         &K_lds[row * 512]);
            }
        }

        // ---- PV: P (LDS, swizzled) x Vt (JIT regs, per-kc double-buffer) ----
        {
            const bf16* vp = Vtbase + (size_t)(wid * 64 + lrow) * SEQ + m0 + lhi * 8;
            bf16x8 vfk[2][4];
            #pragma unroll
            for (int ht = 0; ht < 4; ++ht)
                vfk[0][ht] = *reinterpret_cast<const bf16x8*>(vp + (size_t)(ht * 16) * SEQ);
            #pragma unroll
            for (int kc = 0; kc < 4; ++kc) {
                if (kc + 1 < 4) {
                    #pragma unroll
                    for (int ht = 0; ht < 4; ++ht)
                        vfk[(kc + 1) & 1][ht] = *reinterpret_cast<const bf16x8*>(
                            vp + (size_t)(ht * 16) * SEQ + (kc + 1) * 32);
                }
                __builtin_amdgcn_s_setprio(1);
                #pragma unroll
                for (int t = 0; t < 4; ++t) {
                    const int prow = t * 16 + lrow;
                    const bf16x8 pf = *reinterpret_cast<const bf16x8*>(
                        &P_lds[prow * 128 + (((kc * 4 + lhi) ^ (prow & 7)) * 8)]);
                    #pragma unroll
                    for (int ht = 0; ht < 4; ++ht)
                        acc[t][ht] = mfma16(pf, vfk[kc & 1][ht], acc[t][ht]);
                }
                __builtin_amdgcn_s_setprio(0);
            }
        }

        // B2: lgkm-only — P reads retired (WAR for next writes); K[it+1] stage
        // complete per-wave (via vf in-order waits) -> published block-wide.
        asm volatile("s_waitcnt lgkmcnt(0)" ::: "memory");
        __builtin_amdgcn_s_barrier();
        __builtin_amdgcn_sched_barrier(0);
    }

    // ---- epilogue: reduce l over the 16 lrow lanes per strip, combine strips ----
    #pragma unroll
    for (int rg = 0; rg < 4; ++rg) {
        float sv = l_part[rg];
        sv += __shfl_xor(sv, 1);
        sv += __shfl_xor(sv, 2);
        sv += __shfl_xor(sv, 4);
        sv += __shfl_xor(sv, 8);
        if (lrow == 0) sump_lds[wc][srow_base + rg] = sv;
    }
    __syncthreads();

    // ---- /l, +V, store ----
    #pragma unroll
    for (int t = 0; t < 4; ++t) {
        #pragma unroll
        for (int rg = 0; rg < 4; ++rg) {
            const int row = t * 16 + lhi * 4 + rg;
            const float inv = 1.f / (sump_lds[0][row] + sump_lds[1][row]);
            const size_t rbase = (size_t)(bb * SEQ + n0 + row) * DH;
            #pragma unroll
            for (int ht = 0; ht < 4; ++ht) {
                const int col = wid * 64 + ht * 16 + lrow;
                const float vv = (float)V[rbase + col];
                O[rbase + col] = (bf16)(acc[t][ht][rg] * inv + vv);
            }
        }
    }
}

extern "C" void kernel_launch(void* const* d_in, const int* in_sizes, int n_in,
                              void* d_out, int out_size, void* d_ws, size_t ws_size,
                              hipStream_t stream) {
    const float* A    = (const float*)d_in[0];
    const float* h    = (const float*)d_in[1];
    const float* Wv1  = (const float*)d_in[2];
    const float* bv1  = (const float*)d_in[3];
    const float* Wv2  = (const float*)d_in[4];
    const float* bv2  = (const float*)d_in[5];
    const float* Wk   = (const float*)d_in[6];   // NOTE: Wk before Wq in dict order
    const float* bk   = (const float*)d_in[7];
    const float* Wq   = (const float*)d_in[8];
    const float* bq   = (const float*)d_in[9];
    const float* Wout = (const float*)d_in[10];
    const float* bout = (const float*)d_in[11];
    float* out = (float*)d_out;

    char* ws = (char*)d_ws;
    const size_t SZ = (size_t)ROWS * 512 * sizeof(bf16);  // 33.5 MB
    bf16* hb   = (bf16*)(ws + 0 * SZ);  // h in bf16; later reused as attention output
    bf16* tq   = (bf16*)(ws + 1 * SZ);  // t = relu(h@Wv1), later overwritten with q
    bf16* kb   = (bf16*)(ws + 2 * SZ);
    bf16* vb   = (bf16*)(ws + 3 * SZ);
    bf16* vtb  = (bf16*)(ws + 4 * SZ);  // v transposed: [B][H][N]
    bf16* wbase = (bf16*)(ws + 5 * SZ); // 5 x 512KB bf16 weights
    bf16* Wv1t  = wbase + 0 * 262144;
    bf16* Wv2t  = wbase + 1 * 262144;
    bf16* Wqt   = wbase + 2 * 262144;
    bf16* Wkt   = wbase + 3 * 262144;
    bf16* Woutt = wbase + 4 * 262144;
    bf16* ob = hb;  // attention output aliases hb (hb dead after k projection)

    cvt_all_kernel<<<9216, 256, 0, stream>>>(h, Wv1, Wv2, Wq, Wk, Wout, hb, wbase);

    gemm_relu_kernel<0><<<1024, 256, 0, stream>>>(hb, Wv1t, bv1, tq, nullptr, nullptr);  // t
    gemm_relu_kernel<1><<<1024, 256, 0, stream>>>(tq, Wv2t, bv2, vb, vtb, nullptr);      // v + vT
    gemm_relu_kernel<0><<<1024, 256, 0, stream>>>(hb, Wqt, bq, tq, nullptr, nullptr);    // q (over t)
    gemm_relu_kernel<0><<<1024, 256, 0, stream>>>(hb, Wkt, bk, kb, nullptr, nullptr);    // k

    attn_kernel<<<dim3(512), 512, 0, stream>>>(tq, kb, vtb, vb, A, ob);

    gemm_relu_kernel<2><<<1024, 256, 0, stream>>>(ob, Woutt, bout, nullptr, nullptr, out);
}

// Round 20
// 411.359 us; speedup vs baseline: 1.5155x; 1.0941x over previous
//
#include <hip/hip_runtime.h>

typedef __bf16 bf16;
typedef bf16 bf16x4 __attribute__((ext_vector_type(4)));
typedef bf16 bf16x8 __attribute__((ext_vector_type(8)));
typedef float f32x4 __attribute__((ext_vector_type(4)));

static constexpr int BATCH = 16;
static constexpr int SEQ   = 2048;  // N
static constexpr int DH    = 512;   // H (== M)
static constexpr int ROWS  = BATCH * SEQ;  // 32768

__device__ __forceinline__ f32x4 mfma16(bf16x8 a, bf16x8 b, f32x4 c) {
    return __builtin_amdgcn_mfma_f32_16x16x32_bf16(a, b, c, 0, 0, 0);
}

// async global->LDS, 16B per lane. dst must be wave-uniform base (HW adds lane*16).
__device__ __forceinline__ void gl_lds16(const void* g, void* l) {
    __builtin_amdgcn_global_load_lds((const __attribute__((address_space(1))) void*)g,
                                     (__attribute__((address_space(3))) void*)l, 16, 0, 0);
}

// -------- fused conversions: h fp32->bf16 + 5 weights fp32->[N][K] bf16 --------
__global__ void cvt_all_kernel(const float* __restrict__ h,
                               const float* __restrict__ w0, const float* __restrict__ w1,
                               const float* __restrict__ w2, const float* __restrict__ w3,
                               const float* __restrict__ w4,
                               bf16* __restrict__ hb, bf16* __restrict__ wout) {
    const int b = blockIdx.x;
    if (b < 4096) {
        const int n4 = ROWS * 512 / 4;
        int i = b * 256 + threadIdx.x;
        const int stride = 4096 * 256;
        for (; i < n4; i += stride) {
            f32x4 f = *reinterpret_cast<const f32x4*>(h + (size_t)i * 4);
            bf16x4 o;
            o[0] = (bf16)f[0]; o[1] = (bf16)f[1]; o[2] = (bf16)f[2]; o[3] = (bf16)f[3];
            *reinterpret_cast<bf16x4*>(hb + (size_t)i * 4) = o;
        }
    } else {
        const int bb = b - 4096;
        const int t = bb >> 10;
        const float* in = (t == 0) ? w0 : (t == 1) ? w1 : (t == 2) ? w2 : (t == 3) ? w3 : w4;
        int idx = (bb & 1023) * 256 + threadIdx.x;  // idx = n*512 + k
        int n = idx >> 9, k = idx & 511;
        wout[t * 262144 + idx] = (bf16)in[k * 512 + n];
    }
}

// ---------------- fused t/q/k GEMM: 3 weights over one X panel ----------------
// R20: per block, loop w=0..2 reusing the X row-panel (2nd/3rd stage hits L2,
// saves 2 launches + 67MB HBM). XCD-coherent swizzle as R18. Counted-vmcnt
// double-barrier pipeline per K-step.
__global__ __launch_bounds__(256, 2)
void gemm_tqk_kernel(const bf16* __restrict__ X,
                     const bf16* __restrict__ Wt0, const bf16* __restrict__ Wt1,
                     const bf16* __restrict__ Wt2,
                     const float* __restrict__ b0, const float* __restrict__ b1,
                     const float* __restrict__ b2,
                     bf16* __restrict__ Y0, bf16* __restrict__ Y1, bf16* __restrict__ Y2)
{
    __shared__ bf16 smem[32768];   // 64KB: Xl buf0/1, Wl buf0/1 (16KB each)

    const int tid = threadIdx.x;
    const int lane = tid & 63, wid = tid >> 6;
    const int wr = wid >> 1, wc = wid & 1;
    const int id = blockIdx.x;
    const int r0 = (((id >> 5) << 3) + (id & 7)) * 128;  // row-panel
    const int c0 = ((id >> 3) & 3) * 128;                // col-tile
    const int lrow = lane & 15, lhi = lane >> 4;

    const int srow = tid >> 3;
    const int skb  = (tid & 7) ^ (srow & 7);
    const int sdst = wid * 512;

    for (int w = 0; w < 3; ++w) {
        const bf16* Wt = (w == 0) ? Wt0 : (w == 1) ? Wt1 : Wt2;
        const float* bias = (w == 0) ? b0 : (w == 1) ? b1 : b2;
        bf16* Y = (w == 0) ? Y0 : (w == 1) ? Y1 : Y2;

        auto stage = [&](int buf, int kc) {
            const bf16* xs = X + (size_t)r0 * 512 + kc * 64;
            const bf16* ws = Wt + (size_t)c0 * 512 + kc * 64;
            bf16* Xl = smem + buf * 8192;
            bf16* Wl = smem + 16384 + buf * 8192;
            #pragma unroll
            for (int c = 0; c < 4; ++c) {
                const int row = c * 32 + srow;
                gl_lds16(xs + (size_t)row * 512 + skb * 8, Xl + c * 2048 + sdst);
            }
            #pragma unroll
            for (int c = 0; c < 4; ++c) {
                const int row = c * 32 + srow;
                gl_lds16(ws + (size_t)row * 512 + skb * 8, Wl + c * 2048 + sdst);
            }
        };

        f32x4 acc[4][4] = {};

        stage(0, 0);

        for (int t = 0; t < 8; ++t) {
            const int buf = t & 1;
            if (t + 1 < 8) {
                stage(buf ^ 1, t + 1);
                asm volatile("s_waitcnt vmcnt(8)" ::: "memory");
            } else {
                asm volatile("s_waitcnt vmcnt(0)" ::: "memory");
            }
            __builtin_amdgcn_s_barrier();
            __builtin_amdgcn_sched_barrier(0);

            const bf16* Xl = smem + buf * 8192;
            const bf16* Wl = smem + 16384 + buf * 8192;
            #pragma unroll
            for (int kk = 0; kk < 2; ++kk) {
                bf16x8 af[4], bfr[4];
                const int kb = kk * 4 + lhi;
                #pragma unroll
                for (int tt = 0; tt < 4; ++tt) {
                    const int ra = wr * 64 + tt * 16 + lrow;
                    af[tt] = *reinterpret_cast<const bf16x8*>(&Xl[ra * 64 + ((kb ^ (ra & 7)) * 8)]);
                }
                #pragma unroll
                for (int tt = 0; tt < 4; ++tt) {
                    const int rb = wc * 64 + tt * 16 + lrow;
                    bfr[tt] = *reinterpret_cast<const bf16x8*>(&Wl[rb * 64 + ((kb ^ (rb & 7)) * 8)]);
                }
                #pragma unroll
                for (int i = 0; i < 4; ++i)
                    #pragma unroll
                    for (int j = 0; j < 4; ++j)
                        acc[i][j] = mfma16(af[i], bfr[j], acc[i][j]);
            }

            asm volatile("s_waitcnt lgkmcnt(0)" ::: "memory");
            __builtin_amdgcn_s_barrier();
            __builtin_amdgcn_sched_barrier(0);
        }

        #pragma unroll
        for (int i = 0; i < 4; ++i) {
            #pragma unroll
            for (int j = 0; j < 4; ++j) {
                const int col = c0 + wc * 64 + j * 16 + lrow;
                const float bb = bias[col];
                #pragma unroll
                for (int rg = 0; rg < 4; ++rg) {
                    const int r = r0 + wr * 64 + i * 16 + lhi * 4 + rg;
                    float y = acc[i][j][rg] + bb;
                    y = y > 0.f ? y : 0.f;
                    Y[(size_t)r * 512 + col] = (bf16)y;
                }
            }
        }
        // no barrier needed before next w: next stage writes buf0, whose last
        // reads retired at B2(step6) — all waves are past B2(step7).
    }
}

// ---------------- GEMM: Y = relu(X[R,512] @ W[512,512] + b), LDS staged ----
// OMODE 1: also write transposed copy via LDS (coalesced bf16x8 stores).
// OMODE 2: fp32 out.
template <int OMODE>
__global__ __launch_bounds__(256, 2)
void gemm_relu_kernel(const bf16* __restrict__ X, const bf16* __restrict__ Wt,
                      const float* __restrict__ bias,
                      bf16* __restrict__ Y, bf16* __restrict__ Yt,
                      float* __restrict__ Yf)
{
    __shared__ bf16 smem[32768];   // 64KB; reused as transpose tile in epilogue

    const int tid = threadIdx.x;
    const int lane = tid & 63, wid = tid >> 6;
    const int wr = wid >> 1, wc = wid & 1;
    const int id = blockIdx.x;
    const int r0 = (((id >> 5) << 3) + (id & 7)) * 128;  // row-panel
    const int c0 = ((id >> 3) & 3) * 128;                // col-tile
    const int lrow = lane & 15, lhi = lane >> 4;

    const int srow = tid >> 3;
    const int skb  = (tid & 7) ^ (srow & 7);
    const int sdst = wid * 512;

    auto stage = [&](int buf, int kc) {
        const bf16* xs = X + (size_t)r0 * 512 + kc * 64;
        const bf16* ws = Wt + (size_t)c0 * 512 + kc * 64;
        bf16* Xl = smem + buf * 8192;
        bf16* Wl = smem + 16384 + buf * 8192;
        #pragma unroll
        for (int c = 0; c < 4; ++c) {
            const int row = c * 32 + srow;
            gl_lds16(xs + (size_t)row * 512 + skb * 8, Xl + c * 2048 + sdst);
        }
        #pragma unroll
        for (int c = 0; c < 4; ++c) {
            const int row = c * 32 + srow;
            gl_lds16(ws + (size_t)row * 512 + skb * 8, Wl + c * 2048 + sdst);
        }
    };

    f32x4 acc[4][4] = {};

    stage(0, 0);

    for (int t = 0; t < 8; ++t) {
        const int buf = t & 1;
        if (t + 1 < 8) {
            stage(buf ^ 1, t + 1);
            asm volatile("s_waitcnt vmcnt(8)" ::: "memory");
        } else {
            asm volatile("s_waitcnt vmcnt(0)" ::: "memory");
        }
        __builtin_amdgcn_s_barrier();
        __builtin_amdgcn_sched_barrier(0);

        const bf16* Xl = smem + buf * 8192;
        const bf16* Wl = smem + 16384 + buf * 8192;
        #pragma unroll
        for (int kk = 0; kk < 2; ++kk) {
            bf16x8 af[4], bfr[4];
            const int kb = kk * 4 + lhi;
            #pragma unroll
            for (int tt = 0; tt < 4; ++tt) {
                const int ra = wr * 64 + tt * 16 + lrow;
                af[tt] = *reinterpret_cast<const bf16x8*>(&Xl[ra * 64 + ((kb ^ (ra & 7)) * 8)]);
            }
            #pragma unroll
            for (int tt = 0; tt < 4; ++tt) {
                const int rb = wc * 64 + tt * 16 + lrow;
                bfr[tt] = *reinterpret_cast<const bf16x8*>(&Wl[rb * 64 + ((kb ^ (rb & 7)) * 8)]);
            }
            #pragma unroll
            for (int i = 0; i < 4; ++i)
                #pragma unroll
                for (int j = 0; j < 4; ++j)
                    acc[i][j] = mfma16(af[i], bfr[j], acc[i][j]);
        }

        asm volatile("s_waitcnt lgkmcnt(0)" ::: "memory");
        __builtin_amdgcn_s_barrier();
        __builtin_amdgcn_sched_barrier(0);
    }

    #pragma unroll
    for (int i = 0; i < 4; ++i) {
        #pragma unroll
        for (int j = 0; j < 4; ++j) {
            const int col = c0 + wc * 64 + j * 16 + lrow;
            const float bb = bias[col];
            #pragma unroll
            for (int rg = 0; rg < 4; ++rg) {
                const int r = r0 + wr * 64 + i * 16 + lhi * 4 + rg;
                float y = acc[i][j][rg] + bb;
                y = y > 0.f ? y : 0.f;
                if (OMODE == 2) {
                    Yf[(size_t)r * 512 + col] = y;
                } else {
                    Y[(size_t)r * 512 + col] = (bf16)y;
                    if (OMODE == 1) {
                        // stash transposed into LDS tile (stride 136)
                        smem[(wc * 64 + j * 16 + lrow) * 136
                             + (wr * 64 + i * 16 + lhi * 4 + rg)] = (bf16)y;
                    }
                }
            }
        }
    }

    if (OMODE == 1) {
        __syncthreads();
        // coalesced write-out: Yt[bi*512 + c0+hr][nn0 + n], 128 h-rows x 128 n
        const int hr = tid >> 1, half = tid & 1;
        const size_t obase = ((size_t)(r0 >> 11) * 512 + c0 + hr) * 2048
                             + (r0 & 2047) + half * 64;
        #pragma unroll
        for (int c = 0; c < 8; ++c) {
            bf16x8 v = *reinterpret_cast<const bf16x8*>(&smem[hr * 136 + half * 64 + c * 8]);
            *reinterpret_cast<bf16x8*>(&Yt[obase + c * 8]) = v;
        }
    }
}

// ---------------- fused attention (R19-exact, ~300us) ----------------
// max==0 softmax (q,k>=0, A in [0,1) => scores<=0): p = exp(x) directly,
// l per-lane, reduced once at epilogue. KVBLK=128 (16 iters). K single-buffered
// (128KB), staged after B1. P_lds stride 128 + 16B-block XOR swizzle.
// s_setprio(1) around both MFMA clusters (T5).
__global__ __launch_bounds__(512, 1)
void attn_kernel(const bf16* __restrict__ Q, const bf16* __restrict__ K,
                 const bf16* __restrict__ Vt, const bf16* __restrict__ V,
                 const float* __restrict__ A, bf16* __restrict__ O)
{
    __shared__ bf16 K_lds[128 * 512];     // 128KB, XOR-swizzled rows, single buffer
    __shared__ bf16 P_lds[64 * 128];      // 16KB, stride 128, XOR-swizzled 16B blocks
    __shared__ float sump_lds[2][64];     // per-strip l partials (epilogue only)

    const int tid = threadIdx.x;
    const int lane = tid & 63, wid = tid >> 6;
    const int wr = wid >> 1, wc = wid & 1;
    const int lrow = lane & 15, lhi = lane >> 4;

    // XCD x handles batches {2x, 2x+1}
    const int id = blockIdx.x;
    const int xcd = id & 7, j = id >> 3;
    const int bb = 2 * xcd + (j >> 5);
    const int n0 = (j & 31) * 64;
    const int srow_base = wr * 16 + lhi * 4;

    const bf16* Kbase  = K + (size_t)bb * SEQ * DH;
    const bf16* Vtbase = Vt + (size_t)bb * DH * SEQ;

    // stage K[0]: 128 rows, 16 per wave
    #pragma unroll
    for (int c = 0; c < 16; ++c) {
        const int row = wid * 16 + c;
        gl_lds16(Kbase + (size_t)row * DH + ((lane ^ (row & 7)) * 8), &K_lds[row * 512]);
    }

    // Q resident: rows n0 + wr*16 + lrow (wc pair loads same rows). 64 VGPR.
    bf16x8 qf[16];
    {
        const bf16* qp = Q + (size_t)(bb * SEQ + n0 + wr * 16 + lrow) * DH + lhi * 8;
        #pragma unroll
        for (int kk = 0; kk < 16; ++kk)
            qf[kk] = *reinterpret_cast<const bf16x8*>(qp + kk * 32);
    }

    float l_part[4] = {};      // per-lane denominator partials (rows srow_base+rg)
    f32x4 acc[4][4] = {};      // [q-row-tile][h-tile of this wave's 64-col slice]

    __syncthreads();  // K[0] drained + published

    for (int it = 0; it < 16; ++it) {
        const int m0 = it * 128;

        // A for this iter (consumed after QK^T). 16 loads.
        float av[16];  // [sc*4 + rg]
        {
            const float* ap = A + ((size_t)bb * SEQ + n0 + srow_base) * SEQ + m0 + wc * 64 + lrow;
            #pragma unroll
            for (int sc = 0; sc < 4; ++sc)
                #pragma unroll
                for (int rg = 0; rg < 4; ++rg)
                    av[sc * 4 + rg] = ap[(size_t)rg * SEQ + sc * 16];
        }

        // ---- QK^T: S[16 rows x 64-col strip] from K_lds (4 indep chains) ----
        f32x4 s[4] = {};
        {
            __builtin_amdgcn_s_setprio(1);
            #pragma unroll
            for (int kk = 0; kk < 16; ++kk) {
                const int ks = kk * 4 + lhi;
                #pragma unroll
                for (int sc = 0; sc < 4; ++sc) {
                    const int kr = wc * 64 + sc * 16 + lrow;
                    bf16x8 kf = *reinterpret_cast<const bf16x8*>(
                        &K_lds[kr * 512 + ((ks ^ (kr & 7)) * 8)]);
                    s[sc] = mfma16(qf[kk], kf, s[sc]);
                }
            }
            __builtin_amdgcn_s_setprio(0);
        }

        // ---- p = exp(score * -A) (max==0); P -> LDS (swizzled); l accumulate ----
        #pragma unroll
        for (int sc = 0; sc < 4; ++sc) {
            #pragma unroll
            for (int rg = 0; rg < 4; ++rg) {
                const float p = __expf(s[sc][rg] * (-av[sc * 4 + rg]));
                const int row = srow_base + rg;
                const int blk = wc * 8 + sc * 2 + (lrow >> 3);   // col>>3
                P_lds[row * 128 + ((blk ^ (row & 7)) * 8) + (lrow & 7)] = (bf16)p;
                l_part[rg] += p;
            }
        }

        // B1: lgkm-only — P writes + K reads retired; VMEM stays in flight
        asm volatile("s_waitcnt lgkmcnt(0)" ::: "memory");
        __builtin_amdgcn_s_barrier();
        __builtin_amdgcn_sched_barrier(0);

        // stage K[it+1] into the SAME buffer (WAR-safe: all K reads retired at
        // B1). Completion: vf loads below issued AFTER these; PV's vf wait
        // (in-order vmcnt) forces stage completion; B2 publishes block-wide.
        if (it + 1 < 16) {
            #pragma unroll
            for (int c = 0; c < 16; ++c) {
                const int row = wid * 16 + c;
                gl_lds16(Kbase + (size_t)(m0 + 128 + row) * DH + ((lane ^ (row & 7)) * 8),
                         &K_lds[row * 512]);
            }
        }

        // ---- PV: P (LDS, swizzled) x Vt (JIT regs, per-kc double-buffer) ----
        {
            const bf16* vp = Vtbase + (size_t)(wid * 64 + lrow) * SEQ + m0 + lhi * 8;
            bf16x8 vfk[2][4];
            #pragma unroll
            for (int ht = 0; ht < 4; ++ht)
                vfk[0][ht] = *reinterpret_cast<const bf16x8*>(vp + (size_t)(ht * 16) * SEQ);
            #pragma unroll
            for (int kc = 0; kc < 4; ++kc) {
                if (kc + 1 < 4) {
                    #pragma unroll
                    for (int ht = 0; ht < 4; ++ht)
                        vfk[(kc + 1) & 1][ht] = *reinterpret_cast<const bf16x8*>(
                            vp + (size_t)(ht * 16) * SEQ + (kc + 1) * 32);
                }
                __builtin_amdgcn_s_setprio(1);
                #pragma unroll
                for (int t = 0; t < 4; ++t) {
                    const int prow = t * 16 + lrow;
                    const bf16x8 pf = *reinterpret_cast<const bf16x8*>(
                        &P_lds[prow * 128 + (((kc * 4 + lhi) ^ (prow & 7)) * 8)]);
                    #pragma unroll
                    for (int ht = 0; ht < 4; ++ht)
                        acc[t][ht] = mfma16(pf, vfk[kc & 1][ht], acc[t][ht]);
                }
                __builtin_amdgcn_s_setprio(0);
            }
        }

        // B2: lgkm-only — P reads retired (WAR for next writes); K[it+1] stage
        // complete per-wave (via vf in-order waits) -> published block-wide.
        asm volatile("s_waitcnt lgkmcnt(0)" ::: "memory");
        __builtin_amdgcn_s_barrier();
        __builtin_amdgcn_sched_barrier(0);
    }

    // ---- epilogue: reduce l over the 16 lrow lanes per strip, combine strips ----
    #pragma unroll
    for (int rg = 0; rg < 4; ++rg) {
        float sv = l_part[rg];
        sv += __shfl_xor(sv, 1);
        sv += __shfl_xor(sv, 2);
        sv += __shfl_xor(sv, 4);
        sv += __shfl_xor(sv, 8);
        if (lrow == 0) sump_lds[wc][srow_base + rg] = sv;
    }
    __syncthreads();

    // ---- /l, +V, store ----
    #pragma unroll
    for (int t = 0; t < 4; ++t) {
        #pragma unroll
        for (int rg = 0; rg < 4; ++rg) {
            const int row = t * 16 + lhi * 4 + rg;
            const float inv = 1.f / (sump_lds[0][row] + sump_lds[1][row]);
            const size_t rbase = (size_t)(bb * SEQ + n0 + row) * DH;
            #pragma unroll
            for (int ht = 0; ht < 4; ++ht) {
                const int col = wid * 64 + ht * 16 + lrow;
                const float vv = (float)V[rbase + col];
                O[rbase + col] = (bf16)(acc[t][ht][rg] * inv + vv);
            }
        }
    }
}

extern "C" void kernel_launch(void* const* d_in, const int* in_sizes, int n_in,
                              void* d_out, int out_size, void* d_ws, size_t ws_size,
                              hipStream_t stream) {
    const float* A    = (const float*)d_in[0];
    const float* h    = (const float*)d_in[1];
    const float* Wv1  = (const float*)d_in[2];
    const float* bv1  = (const float*)d_in[3];
    const float* Wv2  = (const float*)d_in[4];
    const float* bv2  = (const float*)d_in[5];
    const float* Wk   = (const float*)d_in[6];   // NOTE: Wk before Wq in dict order
    const float* bk   = (const float*)d_in[7];
    const float* Wq   = (const float*)d_in[8];
    const float* bq   = (const float*)d_in[9];
    const float* Wout = (const float*)d_in[10];
    const float* bout = (const float*)d_in[11];
    float* out = (float*)d_out;

    char* ws = (char*)d_ws;
    const size_t SZ = (size_t)ROWS * 512 * sizeof(bf16);  // 33.5 MB
    bf16* hb   = (bf16*)(ws + 0 * SZ);  // h bf16; dead after tqk -> vtb aliases it
    bf16* tb   = (bf16*)(ws + 1 * SZ);  // t; dead after v-GEMM -> ob aliases it
    bf16* qb   = (bf16*)(ws + 2 * SZ);
    bf16* kb   = (bf16*)(ws + 3 * SZ);
    bf16* vb   = (bf16*)(ws + 4 * SZ);
    bf16* wbase = (bf16*)(ws + 5 * SZ); // 5 x 512KB bf16 weights
    bf16* Wv1t  = wbase + 0 * 262144;
    bf16* Wv2t  = wbase + 1 * 262144;
    bf16* Wqt   = wbase + 2 * 262144;
    bf16* Wkt   = wbase + 3 * 262144;
    bf16* Woutt = wbase + 4 * 262144;
    bf16* vtb = hb;  // v transposed [B][H][N]; hb dead after gemm_tqk
    bf16* ob  = tb;  // attention output; tb dead after v-GEMM

    cvt_all_kernel<<<9216, 256, 0, stream>>>(h, Wv1, Wv2, Wq, Wk, Wout, hb, wbase);

    // t, q, k in ONE launch (X panel staged once per weight; L2-hot for w>=1)
    gemm_tqk_kernel<<<1024, 256, 0, stream>>>(hb, Wv1t, Wqt, Wkt, bv1, bq, bk,
                                              tb, qb, kb);

    // v = relu(t @ Wv2 + b), plus coalesced transposed copy vtb
    gemm_relu_kernel<1><<<1024, 256, 0, stream>>>(tb, Wv2t, bv2, vb, vtb, nullptr);

    attn_kernel<<<dim3(512), 512, 0, stream>>>(qb, kb, vtb, vb, A, ob);

    gemm_relu_kernel<2><<<1024, 256, 0, stream>>>(ob, Woutt, bout, nullptr, nullptr, out);
}